// Round 16
// baseline (55.277 us; speedup 1.0000x reference)
//
#include <hip/hip_runtime.h>
#include <math.h>

// ---------------- problem constants ----------------
#define NROWS 32768   // B*T independent rows (alpha=exp(-50): scan decouples, verified R1)
#define NK 256        // IN_F
#define NF 256        // F
#define NT_SEQ 256    // T
#define MTILE 32      // rows per gemm block (4 waves x [32 rows x 64 cols])
#define TAU 8e-3f     // bf16 vs fp64 ambiguity band (validated R10/R12/R14/R15: absmax 0.0)

// Verified facts (R1..R15, absmax == 0.0 throughout):
//  * v_mem(t) == cur(t) exactly; rows independent; LN collapses to closed form.
//  * fp64 dot (fixed order) reproduces np's spike decisions; coalesced via W^T.
//  * MFMA fragment mapping (A: row=lane&15, k=(lane>>4)*8+j; B: col=lane&15;
//    C/D: col=lane&15, row=(lane>>4)*4+reg) correct.
//  * bf16 single-comp GEMM + TAU=8e-3 + fp64 recheck: exact.
// R16: FULL FISSION into pure streaming kernels. pre_a converts spikes ->
// bf16 A-fragment layout (coalesced in via LDS bounce, coalesced out).
// gemm reads A-frags as contiguous 1KB wave-loads (identity: (l>>4)*16+(l&15)
// == l), no LDS, no stage, no K-loop barriers. Tail = R14's verified code.

typedef __attribute__((ext_vector_type(4))) float f32x4;
typedef __attribute__((ext_vector_type(8))) short bf16x8;

__device__ __forceinline__ unsigned short bf16_rne(float f) {
    unsigned int u = __builtin_bit_cast(unsigned int, f);
    u += 0x7FFFu + ((u >> 16) & 1u);       // round-to-nearest-even
    return (unsigned short)(u >> 16);
}

// ---- k0: W -> bf16 MFMA-B-fragment order (verified R3..R15) + fp32 W^T ----
__global__ void prep_w(const float* __restrict__ W,
                       unsigned short* __restrict__ wt,
                       float* __restrict__ wtT) {
    const int k = blockIdx.x;       // 0..255
    const int col = threadIdx.x;    // 0..255
    const float w = W[k * NF + col];
    const int ks = k >> 5, chunk = (k >> 3) & 3, j = k & 7;
    wt[(ks * 4 + chunk) * 2048 + col * 8 + j] = bf16_rne(w);
    wtT[col * NK + k] = w;          // fp32 transpose for coalesced recheck
}

// ---- k1: spikes -> bf16 A-fragment layout (pure streaming) ----
// at[g][ks][c][r][j] shorts: element = bf16(spikes[g*16+r][ks*32+c*8+j]).
// Per (g,ks) block of 512 shorts (1KB): lane l of gemm reads offset l*8.
__global__ __launch_bounds__(512)
void pre_a(const float* __restrict__ spikes, unsigned short* __restrict__ at) {
    __shared__ __align__(16) short alds[16][264];   // 8.4 KB, 2-way banks
    const int tid = threadIdx.x;
    const int g = blockIdx.x;                       // 16-row group, 0..2047

    // coalesced stage: thread reads 8 consecutive floats of one row
    {
        const int r = tid >> 5, c8 = (tid & 31) * 8;
        const float* p = spikes + (size_t)(g * 16 + r) * NK + c8;
        const float4 u = *reinterpret_cast<const float4*>(p);
        const float4 v = *reinterpret_cast<const float4*>(p + 4);
        const unsigned int w0 = (unsigned int)bf16_rne(u.x) | ((unsigned int)bf16_rne(u.y) << 16);
        const unsigned int w1 = (unsigned int)bf16_rne(u.z) | ((unsigned int)bf16_rne(u.w) << 16);
        const unsigned int w2 = (unsigned int)bf16_rne(v.x) | ((unsigned int)bf16_rne(v.y) << 16);
        const unsigned int w3 = (unsigned int)bf16_rne(v.z) | ((unsigned int)bf16_rne(v.w) << 16);
        *reinterpret_cast<uint4*>(&alds[r][c8]) = make_uint4(w0, w1, w2, w3);
    }
    __syncthreads();

    // coalesced fragment write: thread t = (ks=t>>6, c=(t>>4)&3, r=t&15)
    // gathers alds[r][ks*32+c*8 .. +7] -> at[group] + t*8 (16B, contiguous)
    const int ks = tid >> 6, c = (tid >> 4) & 3, r = tid & 15;
    const uint4 frag = *reinterpret_cast<const uint4*>(&alds[r][ks * 32 + c * 8]);
    *reinterpret_cast<uint4*>(at + (size_t)g * 4096 + tid * 8) = frag;
}

// ---- k2: barrier-free-K bf16 GEMM + spike + recheck + closed-form LN ----
__global__ __launch_bounds__(256)
void lif_gemm(const float* __restrict__ spikes,
              const float* __restrict__ bias,
              const float* __restrict__ ln_scale,
              const float* __restrict__ ln_bias,
              const unsigned short* __restrict__ wt,
              const float* __restrict__ wtT,
              const unsigned short* __restrict__ at,
              float* __restrict__ out)
{
    __shared__ unsigned int bits[MTILE][8];    // 256-bit row masks
    __shared__ float rinv_s[MTILE], mu_s[MTILE];
    __shared__ unsigned int elist[256];        // in-band worklist
    __shared__ int ecnt;

    const int tid = threadIdx.x;
    const int lane = tid & 63;
    const int wid = tid >> 6;                  // 0..3: cols [wid*64, +64)
    const int row0 = blockIdx.x * MTILE;
    const int gg = blockIdx.x * 2;             // first 16-row group

    if (tid == 0) ecnt = 0;
    __syncthreads();

    // A-fragment pointers: contiguous 16B per lane, 1KB per wave-load
    const unsigned short* a0 = at + (size_t)gg * 4096 + lane * 8;        // mt=0
    const unsigned short* a1 = at + (size_t)(gg + 1) * 4096 + lane * 8;  // mt=1
    const int b_base = (lane >> 4) * 2048 + (wid * 64 + (lane & 15)) * 8;

    f32x4 acc[2][4];   // [mt][nt]
    {
        const f32x4 z = {0.f, 0.f, 0.f, 0.f};
        #pragma unroll
        for (int mt = 0; mt < 2; ++mt)
            #pragma unroll
            for (int nt = 0; nt < 4; ++nt) acc[mt][nt] = z;
    }

    // ---- K loop: pure loads + MFMA, no LDS, no barriers, no cvt ----
    #pragma unroll
    for (int ks = 0; ks < 8; ++ks) {
        const bf16x8 fa0 = *reinterpret_cast<const bf16x8*>(a0 + ks * 512);
        const bf16x8 fa1 = *reinterpret_cast<const bf16x8*>(a1 + ks * 512);
        #pragma unroll
        for (int nt = 0; nt < 4; ++nt) {
            const bf16x8 b = *reinterpret_cast<const bf16x8*>(
                wt + ks * 8192 + b_base + nt * 128);
            acc[0][nt] = __builtin_amdgcn_mfma_f32_16x16x32_bf16(fa0, b, acc[0][nt], 0, 0, 0);
            acc[1][nt] = __builtin_amdgcn_mfma_f32_16x16x32_bf16(fa1, b, acc[1][nt], 0, 0, 0);
        }
    }

    // ---- decisions; in-band elements -> worklist (R14-verified) ----
    unsigned int smask[2] = {0u, 0u};   // bit nt*4+reg
    #pragma unroll
    for (int mt = 0; mt < 2; ++mt)
        #pragma unroll
        for (int nt = 0; nt < 4; ++nt) {
            const int gcol = wid * 64 + nt * 16 + (lane & 15);
            const float bv = bias[gcol];
            #pragma unroll
            for (int reg = 0; reg < 4; ++reg) {
                const float v = acc[mt][nt][reg] + bv;
                if ((v - 0.5f) > 0.0f) smask[mt] |= 1u << (nt * 4 + reg);
                if (__builtin_expect(fabsf(v - 0.5f) < TAU, 0)) {
                    const int rl = mt * 16 + (lane >> 4) * 4 + reg;
                    const int ei = atomicAdd(&ecnt, 1);
                    if (ei < 256) elist[ei] = (unsigned int)((rl << 8) | gcol);
                }
            }
        }

    // ---- assemble row masks (R14-verified) ----
    #pragma unroll
    for (int mt = 0; mt < 2; ++mt)
        #pragma unroll
        for (int reg = 0; reg < 4; ++reg) {
            unsigned long long m[4];
            #pragma unroll
            for (int nt = 0; nt < 4; ++nt)
                m[nt] = __ballot((smask[mt] >> (nt * 4 + reg)) & 1u);
            if (lane < 4) {
                const int g = lane;
                const unsigned int w0 =
                    (unsigned int)((m[0] >> (g * 16)) & 0xFFFFull) |
                    ((unsigned int)((m[1] >> (g * 16)) & 0xFFFFull) << 16);
                const unsigned int w1 =
                    (unsigned int)((m[2] >> (g * 16)) & 0xFFFFull) |
                    ((unsigned int)((m[3] >> (g * 16)) & 0xFFFFull) << 16);
                const int rl = mt * 16 + g * 4 + reg;
                bits[rl][wid * 2 + 0] = w0;
                bits[rl][wid * 2 + 1] = w1;
            }
        }
    __syncthreads();

    // ---- coalesced exact fp64 recheck (W^T; R12-verified) ----
    const int ne = min(ecnt, 256);
    for (int e = wid; e < ne; e += 4) {
        const unsigned int pk = elist[e];
        const int rl = (int)(pk >> 8), gcol = (int)(pk & 255u);
        const float* sr = spikes + (size_t)(row0 + rl) * NK;
        const float* wc = wtT + (size_t)gcol * NK;
        const int k0 = lane * 4;
        const float4 s4 = *reinterpret_cast<const float4*>(sr + k0);
        const float4 w4 = *reinterpret_cast<const float4*>(wc + k0);
        const double p0 = (double)s4.x * (double)w4.x;
        const double p1 = (double)s4.y * (double)w4.y;
        const double p2 = (double)s4.z * (double)w4.z;
        const double p3 = (double)s4.w * (double)w4.w;
        double pl = (p0 + p1) + (p2 + p3);
        #pragma unroll
        for (int off = 32; off > 0; off >>= 1) pl += __shfl_down(pl, off);
        if (lane == 0) {
            const double vex = pl + (double)bias[gcol];
            const bool sex = (vex - 0.5) > 0.0;
            const bool spv = (bits[rl][gcol >> 5] >> (gcol & 31)) & 1u;
            if (sex != spv) atomicXor(&bits[rl][gcol >> 5], 1u << (gcol & 31));
        }
    }
    __syncthreads();

    // ---- per-row stats (identical double math to R1..R15) ----
    if (tid < MTILE) {
        int kc = 0;
        #pragma unroll
        for (int w = 0; w < 8; ++w) kc += __popc(bits[tid][w]);
        const double mu = (double)kc * (1.0 / 256.0);
        const double var = mu * (1.0 - mu);
        rinv_s[tid] = (float)(1.0 / sqrt(var + 1e-6));
        mu_s[tid] = (float)mu;
    }
    __syncthreads();

    // ---- LN epilogue + coalesced float4 store (R14-verified) ----
    const int orow = tid >> 3;           // 0..31
    const int of0 = (tid & 7) * 4;       // 0..28
    const int grow = row0 + orow;
    const int t = grow & (NT_SEQ - 1);
    const float rinv = rinv_s[orow];
    const float muf = mu_s[orow];
    #pragma unroll
    for (int j = 0; j < 8; ++j) {
        const int f = of0 + j * 32;
        const unsigned int wb = bits[orow][j];   // f>>5 == j since of0 < 32
        const int sh = of0;
        const float4 g4 = *reinterpret_cast<const float4*>(&ln_scale[t * NF + f]);
        const float4 b4 = *reinterpret_cast<const float4*>(&ln_bias[t * NF + f]);
        float4 o;
        const float s0 = ((wb >> (sh + 0)) & 1u) ? 1.0f : 0.0f;
        const float s1 = ((wb >> (sh + 1)) & 1u) ? 1.0f : 0.0f;
        const float s2 = ((wb >> (sh + 2)) & 1u) ? 1.0f : 0.0f;
        const float s3 = ((wb >> (sh + 3)) & 1u) ? 1.0f : 0.0f;
        o.x = (s0 - muf) * rinv * g4.x + b4.x;
        o.y = (s1 - muf) * rinv * g4.y + b4.y;
        o.z = (s2 - muf) * rinv * g4.z + b4.z;
        o.w = (s3 - muf) * rinv * g4.w + b4.w;
        *reinterpret_cast<float4*>(&out[(size_t)grow * NF + f]) = o;
    }
}

extern "C" void kernel_launch(void* const* d_in, const int* in_sizes, int n_in,
                              void* d_out, int out_size, void* d_ws, size_t ws_size,
                              hipStream_t stream) {
    const float* spikes   = (const float*)d_in[0];
    const float* W        = (const float*)d_in[1];
    const float* bias     = (const float*)d_in[2];
    const float* ln_scale = (const float*)d_in[3];
    const float* ln_bias  = (const float*)d_in[4];
    float* out = (float*)d_out;
    unsigned short* wt = (unsigned short*)d_ws;                 // 128 KB
    float* wtT = (float*)((char*)d_ws + 131072);                // 256 KB fp32 W^T
    unsigned short* at = (unsigned short*)((char*)d_ws + 393216);   // 16 MB A-frags

    prep_w<<<dim3(256), dim3(256), 0, stream>>>(W, wt, wtT);
    pre_a<<<dim3(NROWS / 16), dim3(512), 0, stream>>>(spikes, at);
    lif_gemm<<<dim3(NROWS / MTILE), dim3(256), 0, stream>>>(
        spikes, bias, ln_scale, ln_bias, wt, wtT, at, out);
}